// Round 8
// baseline (195.986 us; speedup 1.0000x reference)
//
#include <hip/hip_runtime.h>
#include <math.h>

// NormalMixtureEM: B=16384 rows, L=512, K=4, 5 EM iters. One wave per row.
// R12 (single controlled change vs R11: __launch_bounds__ min-waves 4 -> 3):
//  - Hypothesis: the persistent ~1.9x gap between static issue count
//    (~4.8k cyc/wave) and measured busy cycles (~9.1k), plus the 14% idle
//    that neither more waves (R7) nor dual-row (R8-R10) fixed, is the
//    COMPILER SERIALIZING the 8 per-sample chains (fma->exp2->add->rcp->
//    mul->fma, ~40cyc latency each) because pipelining them 8-deep needs
//    ~80+ live VGPRs and the (256,4) bound caps the allocator at 64
//    (budget model confirmed by R7/R8/R10: caps 32/64/128 at minw 8/4/2).
//  - (256,3) raises the cap to ~85. HW residency follows ACTUAL usage
//    (~70-85 regs -> ~6 waves/SIMD), at or above the measured ~4.3.
//  - Everything else byte-identical to R11 for a clean A/B.
//  - Pre-committed read: VGPR up + busy up + em down = reg-starved schedule
//    confirmed; VGPR/busy unchanged = issue floor is real -> roofline.
//  - Tripwire: WRITE_SIZE != 131840 KB or FETCH >> 17 MB = spill -> revert.
// R11 (verified, em ~71us): single-row, 48 VGPR, rsq M-step, hoisted
//    g-store bases, merged init wred6, lane-per-component M-step (kk=lane&3),
//    DPP quad_perm intra-quad shuffles, ratio softmax vs component 3
//    (3 exp2 + 1 rcp per sample), interleaved DPP wave reductions,
//    iteration-invariant W{0,1,2} deriving component 3's moments.

constexpr int Bn = 16384;
constexpr int Ln = 512;
constexpr int Kn = 4;
constexpr int NITER = 5;
constexpr float EPSf = 1e-8f;
constexpr float NOISEf = 0.01f;
constexpr float LOG2E = 1.4426950408889634f;

__device__ __forceinline__ float frcp(float v) { return __builtin_amdgcn_rcpf(v); }
__device__ __forceinline__ float frsq(float v) { return __builtin_amdgcn_rsqf(v); }
__device__ __forceinline__ float fexp2(float v) { return __builtin_amdgcn_exp2f(v); }

__device__ __forceinline__ float rlane(float v, int l) {
    return __int_as_float(__builtin_amdgcn_readlane(__float_as_int(v), l));
}

// DPP helpers (VALU pipe; compiler inserts required hazard wait-states).
// quad_perm ctrl byte = sel0 | sel1<<2 | sel2<<4 | sel3<<6.
template <int CTRL>
__device__ __forceinline__ float dpp_mov(float v) {
    return __int_as_float(
        __builtin_amdgcn_update_dpp(0, __float_as_int(v), CTRL, 0xF, 0xF, true));
}
template <int CTRL>
__device__ __forceinline__ float dpp_add(float v) {
    return v + dpp_mov<CTRL>(v);
}

// Interleaved full-wave sums via DPP adds; totals land in lane 63.
// Round-robin keeps same-register DPP reads >=3 instrs apart (hazard-free);
// s_nop 1 guards the asm boundaries.
#define WRED3_STEP(ctrl) \
    "v_add_f32_dpp %0, %0, %0 " ctrl " row_mask:0xf bank_mask:0xf bound_ctrl:0\n\t" \
    "v_add_f32_dpp %1, %1, %1 " ctrl " row_mask:0xf bank_mask:0xf bound_ctrl:0\n\t" \
    "v_add_f32_dpp %2, %2, %2 " ctrl " row_mask:0xf bank_mask:0xf bound_ctrl:0\n\t"

__device__ __forceinline__ void wred3(float& a, float& b, float& c) {
    asm volatile(
        "s_nop 1\n\t"
        WRED3_STEP("row_shr:1")
        WRED3_STEP("row_shr:2")
        WRED3_STEP("row_shr:4")
        WRED3_STEP("row_shr:8")
        WRED3_STEP("row_bcast:15")
        WRED3_STEP("row_bcast:31")
        "s_nop 1"
        : "+v"(a), "+v"(b), "+v"(c));
}

#define WRED6_STEP(ctrl) \
    "v_add_f32_dpp %0, %0, %0 " ctrl " row_mask:0xf bank_mask:0xf bound_ctrl:0\n\t" \
    "v_add_f32_dpp %1, %1, %1 " ctrl " row_mask:0xf bank_mask:0xf bound_ctrl:0\n\t" \
    "v_add_f32_dpp %2, %2, %2 " ctrl " row_mask:0xf bank_mask:0xf bound_ctrl:0\n\t" \
    "v_add_f32_dpp %3, %3, %3 " ctrl " row_mask:0xf bank_mask:0xf bound_ctrl:0\n\t" \
    "v_add_f32_dpp %4, %4, %4 " ctrl " row_mask:0xf bank_mask:0xf bound_ctrl:0\n\t" \
    "v_add_f32_dpp %5, %5, %5 " ctrl " row_mask:0xf bank_mask:0xf bound_ctrl:0\n\t"

__device__ __forceinline__ void wred6(float& a, float& b, float& c,
                                      float& d, float& e, float& f) {
    asm volatile(
        "s_nop 1\n\t"
        WRED6_STEP("row_shr:1")
        WRED6_STEP("row_shr:2")
        WRED6_STEP("row_shr:4")
        WRED6_STEP("row_shr:8")
        WRED6_STEP("row_bcast:15")
        WRED6_STEP("row_bcast:31")
        "s_nop 1"
        : "+v"(a), "+v"(b), "+v"(c), "+v"(d), "+v"(e), "+v"(f));
}

struct RowState {
    float x[8], xx[8], wl[8];
    float muk, wk, invsek, sigk;   // per-lane component k = lane&3
    float blender, prior_p;
    float bm, bv;                  // (1-blender)*mean, (1-blender)*prior_var
    float W0, W1, W2;              // iteration-invariant: sum_l wl*{1, x, x^2}
};

template <bool LAST>
__device__ __forceinline__ void em_iter(RowState& st, float* __restrict__ gp0,
                                        int kk) {
    // Per-lane (k = kk) quadratic coefficients in log2 domain.
    float is2 = st.invsek * st.invsek;
    float lw2 = __log2f((st.wk + EPSf) * st.invsek);
    float Ak = (-0.5f * LOG2E) * is2;
    float Bk = (LOG2E * st.muk) * is2;
    float Ck = fmaf((-0.5f * LOG2E) * (st.muk * st.muk), is2, lw2);
    // Deltas vs component 3 (quad-lane 3) via DPP broadcast; lane kk==3 -> 0.
    float dAl = Ak - dpp_mov<0xFF>(Ak);
    float dBl = Bk - dpp_mov<0xFF>(Bk);
    float dCl = Ck - dpp_mov<0xFF>(Ck);
    // Gather the 9 wave-uniform coefficients into SGPRs.
    float a0 = rlane(dAl, 0), a1 = rlane(dAl, 1), a2 = rlane(dAl, 2);
    float b0 = rlane(dBl, 0), b1 = rlane(dBl, 1), b2 = rlane(dBl, 2);
    float c0 = rlane(dCl, 0), c1 = rlane(dCl, 1), c2 = rlane(dCl, 2);

    float S00 = 0, S01 = 0, S02 = 0;
    float S10 = 0, S11 = 0, S12 = 0;
    float S20 = 0, S21 = 0, S22 = 0;
#pragma unroll
    for (int j = 0; j < 8; ++j) {
        float lm0 = fmaf(a0, st.xx[j], fmaf(b0, st.x[j], c0));
        float lm1 = fmaf(a1, st.xx[j], fmaf(b1, st.x[j], c1));
        float lm2 = fmaf(a2, st.xx[j], fmaf(b2, st.x[j], c2));
        float r0 = fexp2(lm0);
        float r1 = fexp2(lm1);
        float r2 = fexp2(lm2);
        float esum = (r0 + r1) + (r2 + 1.f);   // component 3's ratio is 1
        float inv = frcp(esum);
        float wls = st.wl[j] * inv;
        float wlsx = wls * st.x[j];
        float wlsxx = wls * st.xx[j];
        S00 = fmaf(r0, wls, S00); S10 = fmaf(r0, wlsx, S10); S20 = fmaf(r0, wlsxx, S20);
        S01 = fmaf(r1, wls, S01); S11 = fmaf(r1, wlsx, S11); S21 = fmaf(r1, wlsxx, S21);
        S02 = fmaf(r2, wls, S02); S12 = fmaf(r2, wlsx, S12); S22 = fmaf(r2, wlsxx, S22);
        if (LAST) {
            float4 g4 = make_float4(r0 * inv, r1 * inv, r2 * inv, inv);
            if (j < 4) *(float4*)(gp0 + 4 * j) = g4;
            else       *(float4*)(gp0 + 1024 + 4 * (j - 4)) = g4;
        }
    }

    // Wave-reduce the 9 moments; totals in lane 63 -> SGPRs.
    wred6(S00, S10, S20, S01, S11, S21);
    wred3(S02, S12, S22);
    float s00 = rlane(S00, 63), s10 = rlane(S10, 63), s20 = rlane(S20, 63);
    float s01 = rlane(S01, 63), s11 = rlane(S11, 63), s21 = rlane(S21, 63);
    float s02 = rlane(S02, 63), s12 = rlane(S12, 63), s22 = rlane(S22, 63);
    // Component 3 from iteration-invariant totals (sum_k g = 1).
    float d0 = st.W0 - s00 - s01 - s02;
    float d1 = st.W1 - s10 - s11 - s12;
    float d2 = st.W2 - s20 - s21 - s22;
    // Per-lane selection of this lane's component moments.
    float vT0 = (kk == 0) ? s00 : (kk == 1) ? s01 : (kk == 2) ? s02 : d0;
    float vT1 = (kk == 0) ? s10 : (kk == 1) ? s11 : (kk == 2) ? s12 : d1;
    float vT2 = (kk == 0) ? s20 : (kk == 1) ? s21 : (kk == 2) ? s22 : d2;

    // M-step, one component per lane. Single-pass moments:
    // sum wg*(x-mu)^2 = S2 - 2*mu*S1 + mu^2*S0.
    float sg = fmaxf(vT0, EPSf);
    float rsg = frcp(sg);
    float mun = fmaf(st.blender, vT1 * rsg, st.bm);
    float num = fmaf(mun * mun, vT0, fmaf(-2.f * mun, vT1, vT2));
    float dv = fmaxf(num * rsg, 0.f);
    float var = fmaf(st.blender, dv, st.bv) + EPSf;
    float r = frsq(var);            // invse = rsq(var+eps); sigma = var*r
    st.muk = mun;
    st.sigk = var * r;
    st.invsek = r;
    float wn = sg + st.prior_p;
    // wsum over the 4-lane group via DPP quad_perm butterfly (VALU pipe).
    float ws = dpp_add<0xB1>(wn);   // quad_perm:[1,0,3,2]  (xor 1)
    ws = dpp_add<0x4E>(ws);         // quad_perm:[2,3,0,1]  (xor 2)
    st.wk = wn * frcp(ws);
}

__global__ __launch_bounds__(256, 3) void em_kernel(
    const float* __restrict__ windows,
    const float* __restrict__ centers,
    const float* __restrict__ scales,
    const float* __restrict__ iweights,
    const float* __restrict__ prior_p_param,
    const float* __restrict__ weights_param,
    const float* __restrict__ blend,
    const float* __restrict__ noise,
    float* __restrict__ out_g,
    float* __restrict__ out_w,
    float* __restrict__ out_mu,
    float* __restrict__ out_sigma)
{
    const int lane = threadIdx.x & 63;
    const int kk = lane & 3;
    const int b = blockIdx.x * 4 + (threadIdx.x >> 6);

    RowState st;
    const float* __restrict__ xr = windows + (size_t)b * Ln;
    const float4 q0 = *(const float4*)(xr + 4 * lane);
    const float4 q1 = *(const float4*)(xr + 256 + 4 * lane);
    st.x[0] = q0.x; st.x[1] = q0.y; st.x[2] = q0.z; st.x[3] = q0.w;
    st.x[4] = q1.x; st.x[5] = q1.y; st.x[6] = q1.z; st.x[7] = q1.w;

    const float4 e0 = *(const float4*)(weights_param + 4 * lane);
    const float4 e1 = *(const float4*)(weights_param + 256 + 4 * lane);
    st.wl[0] = __expf(e0.x); st.wl[1] = __expf(e0.y);
    st.wl[2] = __expf(e0.z); st.wl[3] = __expf(e0.w);
    st.wl[4] = __expf(e1.x); st.wl[5] = __expf(e1.y);
    st.wl[6] = __expf(e1.z); st.wl[7] = __expf(e1.w);

    // Row stats + iteration-invariant weighted totals.
    float s = 0.f, ss = 0.f, w0 = 0.f, w1 = 0.f, w2 = 0.f;
#pragma unroll
    for (int j = 0; j < 8; ++j) {
        st.xx[j] = st.x[j] * st.x[j];
        s += st.x[j];
        ss += st.xx[j];
        w0 += st.wl[j];
        w1 = fmaf(st.wl[j], st.x[j], w1);
        w2 = fmaf(st.wl[j], st.xx[j], w2);
    }
    float junk = 0.f;
    wred6(s, ss, w0, w1, w2, junk);
    s = rlane(s, 63);
    ss = rlane(ss, 63);
    st.W0 = rlane(w0, 63);
    st.W1 = rlane(w1, 63);
    st.W2 = rlane(w2, 63);

    const float mean = s * (1.0f / Ln);
    const float var1 = fmaxf((ss - s * mean) * (1.0f / (Ln - 1)), 0.f);
    const float sd = sqrtf(var1);

    st.prior_p = 1.f / (1.f + __expf(-prior_p_param[0]));
    st.blender = 1.f / (1.f + __expf(-blend[0]));
    const float omb = 1.f - st.blender;
    st.bm = omb * mean;
    st.bv = omb * var1;

    // Per-lane component init (k = kk).
    st.muk = fmaf(centers[kk], sd, mean) + noise[(size_t)b * 4 + kk] * sd * NOISEf;
    float sg0 = fabsf(scales[kk]) * sd;
    st.sigk = sg0;
    st.wk = iweights[kk];
    st.invsek = frcp(sg0 + EPSf);

    // Hoisted g-store bases: sample (lane,j<4) -> l = 4*lane+j,
    // (lane,j>=4) -> l = 256+4*lane+(j-4); float offset = 4*l.
    float* gp0 = out_g + (size_t)b * (Ln * Kn) + 16 * lane;

    for (int it = 0; it < NITER - 1; ++it)
        em_iter<false>(st, gp0, kk);
    em_iter<true>(st, gp0, kk);

    if (lane < 4) {
        out_w[(size_t)b * 4 + lane]     = st.wk;
        out_mu[(size_t)b * 4 + lane]    = st.muk;
        out_sigma[(size_t)b * 4 + lane] = st.sigk;
    }
}

extern "C" void kernel_launch(void* const* d_in, const int* in_sizes, int n_in,
                              void* d_out, int out_size, void* d_ws, size_t ws_size,
                              hipStream_t stream) {
    const float* windows       = (const float*)d_in[0];
    const float* init_centers  = (const float*)d_in[1];
    const float* init_scales   = (const float*)d_in[2];
    const float* init_weights  = (const float*)d_in[3];
    const float* prior_p_param = (const float*)d_in[4];
    const float* weights_param = (const float*)d_in[5];
    const float* blend         = (const float*)d_in[6];
    const float* noise         = (const float*)d_in[7];

    float* out       = (float*)d_out;
    float* out_g     = out;                                    // [B, L, K]
    float* out_w     = out_g + (size_t)Bn * Ln * Kn;           // [B, K]
    float* out_mu    = out_w + (size_t)Bn * Kn;                // [B, K]
    float* out_sigma = out_mu + (size_t)Bn * Kn;               // [B, K]

    dim3 grid(Bn / 4);   // 4 waves per block, 1 wave per row
    dim3 block(256);
    hipLaunchKernelGGL(em_kernel, grid, block, 0, stream,
                       windows, init_centers, init_scales, init_weights,
                       prior_p_param, weights_param, blend, noise,
                       out_g, out_w, out_mu, out_sigma);
}